// Round 1
// baseline (2780.866 us; speedup 1.0000x reference)
//
#include <hip/hip_runtime.h>
#include <cstdint>
#include <cstddef>

#define BB 8
#define NQ 2048
#define NK 2048
#define DM 64
#define QT 8
#define NEGC (-1e9f)

__device__ __forceinline__ float frcp(float x){
  float r = __builtin_amdgcn_rcpf(x);
  return r * (2.0f - x*r);   // one Newton step, ~1e-7 rel
}
__device__ __forceinline__ float softplus(float v){
  return fmaxf(v, 0.0f) + log1pf(__expf(-fabsf(v)));
}
__device__ __forceinline__ float wave_sum(float v){
  #pragma unroll
  for (int o = 32; o; o >>= 1) v += __shfl_down(v, o);
  return v;
}
__device__ __forceinline__ float wave_max(float v){
  #pragma unroll
  for (int o = 32; o; o >>= 1) v = fmaxf(v, __shfl_down(v, o));
  return v;
}

// digamma + gammaln for x >= 1 (shift-to-8 + Stirling). abs err < 1e-6.
__device__ __forceinline__ void psi_lgam(float x, float& psi, float& lg){
  float xs = x, csum = 0.0f, prod = 1.0f;
  if (__any(xs < 8.0f)){
    #pragma unroll
    for (int s = 0; s < 7; ++s){
      if (xs < 8.0f){ csum += frcp(xs); prod *= xs; xs += 1.0f; }
    }
  }
  float rx  = frcp(xs);
  float lx  = __logf(xs);
  float rx2 = rx*rx;
  psi = lx - 0.5f*rx
      - rx2*(0.0833333333333f - rx2*(0.00833333333333f - rx2*0.00396825396825f))
      - csum;
  lg  = (xs - 0.5f)*lx - xs + 0.91893853320467274f
      + rx*(0.0833333333333f - rx2*(0.00277777777778f - rx2*0.000793650793651f));
  if (__any(prod != 1.0f)) lg -= __logf(prod);
}

// ---------------- Kernel A: fused 3-layer MLPs (q, k, va) ----------------
__global__ __launch_bounds__(256) void mlp3_kernel(
    const float* __restrict__ y, const float* __restrict__ x,
    const float* __restrict__ Wq, const float* __restrict__ bq,
    const float* __restrict__ Wk, const float* __restrict__ bk,
    const float* __restrict__ Wv, const float* __restrict__ bv,
    float* __restrict__ qo, float* __restrict__ ko, float* __restrict__ vo){
  const int which = blockIdx.y;                 // 0:q 1:k 2:va
  const float* src = (which == 0) ? y : x;
  const float* W   = (which == 0) ? Wq : (which == 1 ? Wk : Wv);
  const float* bb  = (which == 0) ? bq : (which == 1 ? bk : bv);
  float* dst       = (which == 0) ? qo : (which == 1 ? ko : vo);
  const bool last_sp = (which != 2);
  const int row0 = blockIdx.x * 4;
  const int r = threadIdx.x >> 6, c = threadIdx.x & 63;

  __shared__ float h[2][4][DM];
  __shared__ float Wl[DM][DM];

  h[0][r][c] = src[(size_t)(row0 + r)*DM + c];
  float acc = 0.0f;
  for (int l = 0; l < 3; ++l){
    __syncthreads();
    #pragma unroll
    for (int i = 0; i < 16; ++i)
      ((float*)Wl)[i*256 + threadIdx.x] = W[l*DM*DM + i*256 + threadIdx.x];
    __syncthreads();
    float wcol[DM];
    #pragma unroll
    for (int d = 0; d < DM; ++d) wcol[d] = Wl[d][c];
    acc = bb[l*DM + c];
    const float* hr = h[l & 1][r];
    #pragma unroll
    for (int d = 0; d < DM; ++d) acc = fmaf(hr[d], wcol[d], acc);
    if (l < 2 || last_sp) acc = softplus(acc);
    __syncthreads();
    h[(l + 1) & 1][r][c] = acc;
  }
  dst[(size_t)(row0 + r)*DM + c] = acc;
}

// ---------------- Kernel B: main fused attention ----------------
// block = 256 thr, handles QT=8 q-rows of one batch. thread t owns k/j indices
// j = t + 256*i (i=0..7); alpha/z kept in 64 registers.
__global__ __launch_bounds__(256) void bayes_main_kernel(
    const float* __restrict__ qg, const float* __restrict__ kg, const float* __restrict__ vag,
    const float* __restrict__ maskg, const float* __restrict__ epsg,
    float* __restrict__ outg, float* __restrict__ attng, float* __restrict__ klws){
  const int b  = blockIdx.y;
  const int q0 = blockIdx.x * QT;
  const int t  = threadIdx.x;
  const int lane = t & 63, wid = t >> 6;

  __shared__ float4 qlds[QT][16];        // q tile (8 rows x 64)
  __shared__ float4 alds[QT][64];        // attn chunk stage (8 x 256 floats)
  __shared__ float  wr6[4][QT][6];       // per-wave reduction slots
  __shared__ float  rowc1[QT], rowS2[QT], rowmax[QT], rowinv[QT], klrow[QT];

  if (t < 128)
    qlds[t >> 4][t & 15] = ((const float4*)qg)[(size_t)(b*NQ + q0)*16 + t];
  __syncthreads();

  // ---- pass A: qk dots -> alpha in regs ----
  float z[QT][8];
  const float* kb = kg + (size_t)b*NK*DM;
  #pragma unroll
  for (int i = 0; i < 8; ++i){
    float4 kr[16];
    const float4* krow = (const float4*)(kb + (size_t)(i*256 + t)*DM);
    #pragma unroll
    for (int d = 0; d < 16; ++d) kr[d] = krow[d];
    #pragma unroll
    for (int r = 0; r < QT; ++r){
      float acc = 0.0f;
      #pragma unroll
      for (int d = 0; d < 16; ++d){
        float4 qv = qlds[r][d];
        acc = fmaf(qv.x, kr[d].x, acc);
        acc = fmaf(qv.y, kr[d].y, acc);
        acc = fmaf(qv.z, kr[d].z, acc);
        acc = fmaf(qv.w, kr[d].w, acc);
      }
      z[r][i] = acc + 1.0f;              // alpha = qk + 1
    }
  }

  // ---- sweep 1: mask read, dirichlet sums (a0, Sg, Sadg, Sdg, Sinv, latent) ----
  unsigned mb[QT];
  #pragma unroll
  for (int r = 0; r < QT; ++r){
    float a0 = 0, Sg = 0, Sadg = 0, Sdg = 0, Sinv = 0, lat = 0;
    unsigned bits = 0;
    const float* mrow = maskg + ((size_t)(b*NQ) + q0 + r)*NK;
    #pragma unroll
    for (int i = 0; i < 8; ++i){
      float m = mrow[i*256 + t];
      float a = z[r][i];
      if (m != 0.0f) bits |= (1u << i);
      float psi, lg;
      psi_lgam(a, psi, lg);
      float inv = frcp(a);
      a0   = fmaf(a,      m, a0);
      Sg   = fmaf(lg,     m, Sg);
      Sadg = fmaf(a*psi,  m, Sadg);
      Sdg  = fmaf(psi,    m, Sdg);
      Sinv = fmaf(inv,    m, Sinv);
      lat += m;
    }
    mb[r] = bits;
    a0 = wave_sum(a0); Sg = wave_sum(Sg); Sadg = wave_sum(Sadg);
    Sdg = wave_sum(Sdg); Sinv = wave_sum(Sinv); lat = wave_sum(lat);
    if (lane == 0){
      wr6[wid][r][0] = a0;  wr6[wid][r][1] = Sg;  wr6[wid][r][2] = Sadg;
      wr6[wid][r][3] = Sdg; wr6[wid][r][4] = Sinv; wr6[wid][r][5] = lat;
    }
  }
  __syncthreads();
  if (t < QT){
    const int r = t;
    float A0 = 0, SG = 0, SADG = 0, SDG = 0, SINV = 0, LT = 0;
    #pragma unroll
    for (int w = 0; w < 4; ++w){
      A0 += wr6[w][r][0]; SG += wr6[w][r][1]; SADG += wr6[w][r][2];
      SDG += wr6[w][r][3]; SINV += wr6[w][r][4]; LT += wr6[w][r][5];
    }
    float invLT = frcp(LT);
    rowc1[r] = 1.0f - 2.0f*invLT;
    rowS2[r] = SINV*invLT*invLT;
    // KLD combine in fp64 (cancellation of ~4e5-size terms down to ~1e3)
    double A0d = (double)A0, csum = 0.0, prod = 1.0;
    #pragma unroll
    for (int s = 0; s < 7; ++s){
      if (A0d < 8.0){ csum += 1.0/A0d; prod *= A0d; A0d += 1.0; }
    }
    double lx = log(A0d), r1 = 1.0/A0d, r2 = r1*r1;
    double psiA = lx - 0.5*r1
                - r2*((1.0/12.0) - r2*((1.0/120.0) - r2*(1.0/252.0))) - csum;
    double lgA  = (A0d - 0.5)*lx - A0d + 0.918938533204672741
                + r1*((1.0/12.0) - r2*((1.0/360.0) - r2*(1.0/1260.0))) - log(prod);
    double kl = lgA - (double)SG + (double)SADG - psiA*(double)A0
              - ((double)SDG - psiA*(double)LT)*(1.0/(double)NK);
    klrow[r] = (float)fabs(kl);
  }
  __syncthreads();
  if (t == 0){
    float s = 0;
    #pragma unroll
    for (int r = 0; r < QT; ++r) s += klrow[r];
    klws[b*(NQ/QT) + blockIdx.x] = s;
  }

  // ---- sweep 2: z = log(alpha) + sigma*eps (mean-log shift dropped: softmax-invariant) ----
  #pragma unroll
  for (int r = 0; r < QT; ++r){
    const float c1 = rowc1[r], S2 = rowS2[r];
    const float* erow = epsg + ((size_t)(b*NQ) + q0 + r)*NK;
    float mx = -3.4e38f;
    #pragma unroll
    for (int i = 0; i < 8; ++i){
      float e = erow[i*256 + t];
      float a = z[r][i];
      float zz;
      if ((mb[r] >> i) & 1u){
        float la = __logf(a);
        zz = fmaf(fmaf(c1, frcp(a), S2), e, la);
      } else {
        zz = NEGC;
      }
      z[r][i] = zz;
      mx = fmaxf(mx, zz);
    }
    mx = wave_max(mx);
    if (lane == 0) wr6[wid][r][0] = mx;
  }
  __syncthreads();
  if (t < QT)
    rowmax[t] = fmaxf(fmaxf(wr6[0][t][0], wr6[1][t][0]),
                      fmaxf(wr6[2][t][0], wr6[3][t][0]));
  __syncthreads();

  // ---- sweep 3: exp + row sum ----
  #pragma unroll
  for (int r = 0; r < QT; ++r){
    const float mxr = rowmax[r];
    float s = 0.0f;
    #pragma unroll
    for (int i = 0; i < 8; ++i){
      float e2 = __expf(z[r][i] - mxr);
      z[r][i] = e2;
      s += e2;
    }
    s = wave_sum(s);
    if (lane == 0) wr6[wid][r][1] = s;
  }
  __syncthreads();
  if (t < QT)
    rowinv[t] = frcp(wr6[0][t][1] + wr6[1][t][1] + wr6[2][t][1] + wr6[3][t][1]);
  __syncthreads();

  // ---- sweep 4: write attn + out = attn @ va ----
  const float* vb = vag + (size_t)b*NK*DM;
  const int dd = t & 63, rq = t >> 6;
  float acc0 = 0.0f, acc1 = 0.0f;
  #pragma unroll
  for (int i = 0; i < 8; ++i){
    #pragma unroll
    for (int r = 0; r < QT; ++r){
      float av = z[r][i] * rowinv[r];
      attng[((size_t)(b*NQ) + q0 + r)*NK + i*256 + t] = av;
      ((float*)alds)[r*256 + t] = av;
    }
    __syncthreads();
    const float* vchunk = vb + (size_t)i*256*DM;
    #pragma unroll 8
    for (int j4 = 0; j4 < 64; ++j4){
      float4 a0v = alds[rq][j4];
      float4 a1v = alds[rq + 4][j4];
      float v0 = vchunk[(j4*4 + 0)*DM + dd];
      float v1 = vchunk[(j4*4 + 1)*DM + dd];
      float v2 = vchunk[(j4*4 + 2)*DM + dd];
      float v3 = vchunk[(j4*4 + 3)*DM + dd];
      acc0 = fmaf(a0v.x, v0, fmaf(a0v.y, v1, fmaf(a0v.z, v2, fmaf(a0v.w, v3, acc0))));
      acc1 = fmaf(a1v.x, v0, fmaf(a1v.y, v1, fmaf(a1v.z, v2, fmaf(a1v.w, v3, acc1))));
    }
    __syncthreads();
  }
  outg[((size_t)(b*NQ) + q0 + rq)*DM + dd]     = acc0;
  outg[((size_t)(b*NQ) + q0 + rq + 4)*DM + dd] = acc1;
}

// ---------------- Kernel C: deterministic KLD reduce ----------------
__global__ __launch_bounds__(256) void kld_reduce_kernel(
    const float* __restrict__ klws, float* __restrict__ dst){
  float s = 0.0f;
  for (int i = threadIdx.x; i < BB*(NQ/QT); i += 256) s += klws[i];
  s = wave_sum(s);
  __shared__ float w4[4];
  if ((threadIdx.x & 63) == 0) w4[threadIdx.x >> 6] = s;
  __syncthreads();
  if (threadIdx.x == 0)
    dst[0] = (w4[0] + w4[1] + w4[2] + w4[3]) * (1.0f/((float)BB*(float)NQ));
}

extern "C" void kernel_launch(void* const* d_in, const int* in_sizes, int n_in,
                              void* d_out, int out_size, void* d_ws, size_t ws_size,
                              hipStream_t stream){
  const float* y    = (const float*)d_in[0];
  const float* x    = (const float*)d_in[1];
  const float* mask = (const float*)d_in[2];
  const float* eps  = (const float*)d_in[3];
  const float* Wq   = (const float*)d_in[4];
  const float* bq   = (const float*)d_in[5];
  const float* Wk   = (const float*)d_in[6];
  const float* bk   = (const float*)d_in[7];
  const float* Wv   = (const float*)d_in[8];
  const float* bv   = (const float*)d_in[9];

  float* out  = (float*)d_out;                       // [B,NQ,DM]
  float* attn = out  + (size_t)BB*NQ*DM;             // [B,NQ,NK]
  float* va   = attn + (size_t)BB*NQ*NK;             // [B,NK,DM]
  float* kld  = va   + (size_t)BB*NK*DM;             // [1]

  float* qws  = (float*)d_ws;                        // 4 MB
  float* kws  = qws + (size_t)BB*NQ*DM;              // 4 MB
  float* klws = kws + (size_t)BB*NK*DM;              // 8 KB

  dim3 gA((BB*NQ)/4, 3);
  hipLaunchKernelGGL(mlp3_kernel, gA, dim3(256), 0, stream,
                     y, x, Wq, bq, Wk, bk, Wv, bv, qws, kws, va);
  dim3 gB(NQ/QT, BB);
  hipLaunchKernelGGL(bayes_main_kernel, gB, dim3(256), 0, stream,
                     qws, kws, va, mask, eps, out, attn, klws);
  hipLaunchKernelGGL(kld_reduce_kernel, dim3(1), dim3(256), 0, stream, klws, kld);
}

// Round 2
// 687.134 us; speedup vs baseline: 4.0471x; 4.0471x over previous
//
#include <hip/hip_runtime.h>
#include <cstdint>
#include <cstddef>

#define BB 8
#define NQ 2048
#define NK 2048
#define DM 64
#define QT 8
#define NEGC (-1e9f)

__device__ __forceinline__ float frcp(float x){
  float r = __builtin_amdgcn_rcpf(x);
  return r * (2.0f - x*r);   // one Newton step, ~1e-7 rel
}
__device__ __forceinline__ float softplus(float v){
  return fmaxf(v, 0.0f) + log1pf(__expf(-fabsf(v)));
}
__device__ __forceinline__ float wave_sum(float v){
  #pragma unroll
  for (int o = 32; o; o >>= 1) v += __shfl_down(v, o);
  return v;
}
__device__ __forceinline__ float wave_max(float v){
  #pragma unroll
  for (int o = 32; o; o >>= 1) v = fmaxf(v, __shfl_down(v, o));
  return v;
}

// digamma + gammaln for x >= 1 (shift-to-8 + Stirling). abs err < 1e-6.
__device__ __forceinline__ void psi_lgam(float x, float& psi, float& lg){
  float xs = x, csum = 0.0f, prod = 1.0f;
  if (__any(xs < 8.0f)){
    #pragma unroll
    for (int s = 0; s < 7; ++s){
      if (xs < 8.0f){ csum += frcp(xs); prod *= xs; xs += 1.0f; }
    }
  }
  float rx  = frcp(xs);
  float lx  = __logf(xs);
  float rx2 = rx*rx;
  psi = lx - 0.5f*rx
      - rx2*(0.0833333333333f - rx2*(0.00833333333333f - rx2*0.00396825396825f))
      - csum;
  lg  = (xs - 0.5f)*lx - xs + 0.91893853320467274f
      + rx*(0.0833333333333f - rx2*(0.00277777777778f - rx2*0.000793650793651f));
  if (__any(prod != 1.0f)) lg -= __logf(prod);
}

// ---------------- Kernel A: fused 3-layer MLPs (q, k, va) ----------------
__global__ __launch_bounds__(256) void mlp3_kernel(
    const float* __restrict__ y, const float* __restrict__ x,
    const float* __restrict__ Wq, const float* __restrict__ bq,
    const float* __restrict__ Wk, const float* __restrict__ bk,
    const float* __restrict__ Wv, const float* __restrict__ bv,
    float* __restrict__ qo, float* __restrict__ ko, float* __restrict__ vo){
  const int which = blockIdx.y;                 // 0:q 1:k 2:va
  const float* src = (which == 0) ? y : x;
  const float* W   = (which == 0) ? Wq : (which == 1 ? Wk : Wv);
  const float* bb  = (which == 0) ? bq : (which == 1 ? bk : bv);
  float* dst       = (which == 0) ? qo : (which == 1 ? ko : vo);
  const bool last_sp = (which != 2);
  const int row0 = blockIdx.x * 4;
  const int r = threadIdx.x >> 6, c = threadIdx.x & 63;

  __shared__ float h[2][4][DM];
  __shared__ float Wl[DM][DM];

  h[0][r][c] = src[(size_t)(row0 + r)*DM + c];
  float acc = 0.0f;
  for (int l = 0; l < 3; ++l){
    __syncthreads();
    #pragma unroll
    for (int i = 0; i < 16; ++i)
      ((float*)Wl)[i*256 + threadIdx.x] = W[l*DM*DM + i*256 + threadIdx.x];
    __syncthreads();
    float wcol[DM];
    #pragma unroll
    for (int d = 0; d < DM; ++d) wcol[d] = Wl[d][c];
    acc = bb[l*DM + c];
    const float* hr = h[l & 1][r];
    #pragma unroll
    for (int d = 0; d < DM; ++d) acc = fmaf(hr[d], wcol[d], acc);
    if (l < 2 || last_sp) acc = softplus(acc);
    __syncthreads();
    h[(l + 1) & 1][r][c] = acc;
  }
  dst[(size_t)(row0 + r)*DM + c] = acc;
}

// ---------------- Kernel A2: transpose k -> kT[B][DM][NK] ----------------
__global__ __launch_bounds__(256) void ktrans_kernel(
    const float* __restrict__ k, float* __restrict__ kT){
  const int b = blockIdx.y, tile = blockIdx.x;  // tile of 64 rows
  const int t = threadIdx.x;
  __shared__ float ld[64][65];
  const float* src = k + (size_t)b*NK*DM + (size_t)tile*64*DM;
  #pragma unroll
  for (int p = 0; p < 4; ++p){
    int idx = t + p*256;                 // float4 index 0..1023
    int row = idx >> 4, c4 = idx & 15;
    float4 v = ((const float4*)src)[idx];
    ld[row][c4*4+0] = v.x; ld[row][c4*4+1] = v.y;
    ld[row][c4*4+2] = v.z; ld[row][c4*4+3] = v.w;
  }
  __syncthreads();
  float* dst = kT + (size_t)b*DM*NK + (size_t)tile*64;
  #pragma unroll
  for (int p = 0; p < 4; ++p){
    int idx = t + p*256;
    int d = idx >> 4, j4 = idx & 15;
    float4 v = { ld[j4*4+0][d], ld[j4*4+1][d], ld[j4*4+2][d], ld[j4*4+3][d] };
    ((float4*)(dst + (size_t)d*NK))[j4] = v;
  }
}

// ---------------- Kernel B: main fused attention ----------------
// 1-D grid, wg = b + 8*qtile (XCD-friendly: blocks of one batch share an XCD's L2).
// Thread t owns k-indices j = i*256+t (i=0..7); alpha/z kept in 64 registers.
__global__ __launch_bounds__(256, 4) void bayes_main_kernel(
    const float* __restrict__ qg, const float* __restrict__ kTg, const float* __restrict__ vag,
    const float* __restrict__ maskg, const float* __restrict__ epsg,
    float* __restrict__ outg, float* __restrict__ attng, float* __restrict__ klws){
  const int b  = blockIdx.x & 7;
  const int qt = blockIdx.x >> 3;
  const int q0 = qt * QT;
  const int t  = threadIdx.x;
  const int lane = t & 63, wid = t >> 6;

  __shared__ float4 qlds[QT][16];        // q tile (8 rows x 64)
  __shared__ float  aldsf[QT*256];       // attn chunk stage (8 x 256)
  __shared__ float  wr6[4][QT][6];       // per-wave reduction slots
  __shared__ float  rowc1[QT], rowS2[QT], rowmax[QT], rowinv[QT], klrow[QT];

  if (t < 128)
    qlds[t >> 4][t & 15] = ((const float4*)qg)[(size_t)(b*NQ + q0)*16 + t];
  __syncthreads();

  // ---- pass A: qk dots via coalesced kT streams, z = alpha ----
  float z[QT][8];
  #pragma unroll
  for (int r = 0; r < QT; ++r)
    #pragma unroll
    for (int i = 0; i < 8; ++i) z[r][i] = 1.0f;   // alpha = qk + 1

  const float* kTb = kTg + (size_t)b*DM*NK;
  #pragma unroll 1
  for (int dblk = 0; dblk < 16; ++dblk){
    float4 qv[QT];
    #pragma unroll
    for (int r = 0; r < QT; ++r) qv[r] = qlds[r][dblk];
    const float* kc0 = kTb + (size_t)(dblk*4)*NK + t;
    #pragma unroll
    for (int i = 0; i < 8; ++i){
      float k0 = kc0[i*256];
      float k1 = kc0[i*256 + NK];
      float k2 = kc0[i*256 + 2*NK];
      float k3 = kc0[i*256 + 3*NK];
      #pragma unroll
      for (int r = 0; r < QT; ++r){
        float a = z[r][i];
        a = fmaf(k0, qv[r].x, a);
        a = fmaf(k1, qv[r].y, a);
        a = fmaf(k2, qv[r].z, a);
        a = fmaf(k3, qv[r].w, a);
        z[r][i] = a;
      }
    }
  }

  // ---- sweep 1: mask read, dirichlet sums ----
  unsigned mb[QT];
  #pragma unroll
  for (int r = 0; r < QT; ++r){
    float a0 = 0, Sg = 0, Sadg = 0, Sdg = 0, Sinv = 0, lat = 0;
    unsigned bits = 0;
    const float* mrow = maskg + ((size_t)(b*NQ) + q0 + r)*NK;
    #pragma unroll
    for (int i = 0; i < 8; ++i){
      float m = __builtin_nontemporal_load(mrow + i*256 + t);
      float a = z[r][i];
      if (m != 0.0f) bits |= (1u << i);
      float psi, lg;
      psi_lgam(a, psi, lg);
      float inv = frcp(a);
      a0   = fmaf(a,      m, a0);
      Sg   = fmaf(lg,     m, Sg);
      Sadg = fmaf(a*psi,  m, Sadg);
      Sdg  = fmaf(psi,    m, Sdg);
      Sinv = fmaf(inv,    m, Sinv);
      lat += m;
    }
    mb[r] = bits;
    a0 = wave_sum(a0); Sg = wave_sum(Sg); Sadg = wave_sum(Sadg);
    Sdg = wave_sum(Sdg); Sinv = wave_sum(Sinv); lat = wave_sum(lat);
    if (lane == 0){
      wr6[wid][r][0] = a0;  wr6[wid][r][1] = Sg;  wr6[wid][r][2] = Sadg;
      wr6[wid][r][3] = Sdg; wr6[wid][r][4] = Sinv; wr6[wid][r][5] = lat;
    }
  }
  __syncthreads();
  if (t < QT){
    const int r = t;
    float A0 = 0, SG = 0, SADG = 0, SDG = 0, SINV = 0, LT = 0;
    #pragma unroll
    for (int w = 0; w < 4; ++w){
      A0 += wr6[w][r][0]; SG += wr6[w][r][1]; SADG += wr6[w][r][2];
      SDG += wr6[w][r][3]; SINV += wr6[w][r][4]; LT += wr6[w][r][5];
    }
    float invLT = frcp(LT);
    rowc1[r] = 1.0f - 2.0f*invLT;
    rowS2[r] = SINV*invLT*invLT;
    // KLD combine in fp64 (cancellation of ~4e5-size terms down to ~1e3)
    double A0d = (double)A0, csum = 0.0, prod = 1.0;
    #pragma unroll
    for (int s = 0; s < 7; ++s){
      if (A0d < 8.0){ csum += 1.0/A0d; prod *= A0d; A0d += 1.0; }
    }
    double lx = log(A0d), r1 = 1.0/A0d, r2 = r1*r1;
    double psiA = lx - 0.5*r1
                - r2*((1.0/12.0) - r2*((1.0/120.0) - r2*(1.0/252.0))) - csum;
    double lgA  = (A0d - 0.5)*lx - A0d + 0.918938533204672741
                + r1*((1.0/12.0) - r2*((1.0/360.0) - r2*(1.0/1260.0))) - log(prod);
    double kl = lgA - (double)SG + (double)SADG - psiA*(double)A0
              - ((double)SDG - psiA*(double)LT)*(1.0/(double)NK);
    klrow[r] = (float)fabs(kl);
  }
  __syncthreads();
  if (t == 0){
    float s = 0;
    #pragma unroll
    for (int r = 0; r < QT; ++r) s += klrow[r];
    klws[b*(NQ/QT) + qt] = s;
  }

  // ---- sweep 2: z = log(alpha) + sigma*eps (mean-log shift is softmax-invariant) ----
  #pragma unroll
  for (int r = 0; r < QT; ++r){
    const float c1 = rowc1[r], S2 = rowS2[r];
    const float* erow = epsg + ((size_t)(b*NQ) + q0 + r)*NK;
    float mx = -3.4e38f;
    #pragma unroll
    for (int i = 0; i < 8; ++i){
      float e = __builtin_nontemporal_load(erow + i*256 + t);
      float a = z[r][i];
      float zz;
      if ((mb[r] >> i) & 1u){
        float la = __logf(a);
        zz = fmaf(fmaf(c1, frcp(a), S2), e, la);
      } else {
        zz = NEGC;
      }
      z[r][i] = zz;
      mx = fmaxf(mx, zz);
    }
    mx = wave_max(mx);
    if (lane == 0) wr6[wid][r][0] = mx;
  }
  __syncthreads();
  if (t < QT)
    rowmax[t] = fmaxf(fmaxf(wr6[0][t][0], wr6[1][t][0]),
                      fmaxf(wr6[2][t][0], wr6[3][t][0]));
  __syncthreads();

  // ---- sweep 3: exp + row sum ----
  #pragma unroll
  for (int r = 0; r < QT; ++r){
    const float mxr = rowmax[r];
    float s = 0.0f;
    #pragma unroll
    for (int i = 0; i < 8; ++i){
      float e2 = __expf(z[r][i] - mxr);
      z[r][i] = e2;
      s += e2;
    }
    s = wave_sum(s);
    if (lane == 0) wr6[wid][r][1] = s;
  }
  __syncthreads();
  if (t < QT)
    rowinv[t] = frcp(wr6[0][t][1] + wr6[1][t][1] + wr6[2][t][1] + wr6[3][t][1]);
  __syncthreads();

  float rinv[QT];
  #pragma unroll
  for (int r = 0; r < QT; ++r) rinv[r] = rowinv[r];

  // ---- sweep 4: write attn + out = attn @ va (float4 over d) ----
  const float* vb = vag + (size_t)b*NK*DM;
  const int d4 = t & 15;          // float4 column group
  const int rr = (t >> 4) & 7;    // q-row
  const int jh = t >> 7;          // j-half (0/1)
  float4 acc = {0.0f, 0.0f, 0.0f, 0.0f};
  #pragma unroll
  for (int i = 0; i < 8; ++i){
    #pragma unroll
    for (int r = 0; r < QT; ++r){
      float av = z[r][i] * rinv[r];
      __builtin_nontemporal_store(av, attng + ((size_t)(b*NQ) + q0 + r)*NK + i*256 + t);
      aldsf[r*256 + t] = av;
    }
    __syncthreads();
    const float* vchunk = vb + (size_t)(i*256)*DM + d4*4;
    #pragma unroll 4
    for (int jj = 0; jj < 128; ++jj){
      int j = jh*128 + jj;
      float4 v = *(const float4*)(vchunk + (size_t)j*DM);
      float a = aldsf[rr*256 + j];
      acc.x = fmaf(a, v.x, acc.x);
      acc.y = fmaf(a, v.y, acc.y);
      acc.z = fmaf(a, v.z, acc.z);
      acc.w = fmaf(a, v.w, acc.w);
    }
    __syncthreads();
  }
  // combine the two j-halves
  if (jh == 1) *(float4*)&aldsf[(t - 128)*4] = acc;
  __syncthreads();
  if (jh == 0){
    float4 o = *(float4*)&aldsf[t*4];
    acc.x += o.x; acc.y += o.y; acc.z += o.z; acc.w += o.w;
    *(float4*)(outg + ((size_t)(b*NQ) + q0 + rr)*DM + d4*4) = acc;
  }
}

// ---------------- Kernel C: deterministic KLD reduce ----------------
__global__ __launch_bounds__(256) void kld_reduce_kernel(
    const float* __restrict__ klws, float* __restrict__ dst){
  float s = 0.0f;
  for (int i = threadIdx.x; i < BB*(NQ/QT); i += 256) s += klws[i];
  s = wave_sum(s);
  __shared__ float w4[4];
  if ((threadIdx.x & 63) == 0) w4[threadIdx.x >> 6] = s;
  __syncthreads();
  if (threadIdx.x == 0)
    dst[0] = (w4[0] + w4[1] + w4[2] + w4[3]) * (1.0f/((float)BB*(float)NQ));
}

extern "C" void kernel_launch(void* const* d_in, const int* in_sizes, int n_in,
                              void* d_out, int out_size, void* d_ws, size_t ws_size,
                              hipStream_t stream){
  const float* y    = (const float*)d_in[0];
  const float* x    = (const float*)d_in[1];
  const float* mask = (const float*)d_in[2];
  const float* eps  = (const float*)d_in[3];
  const float* Wq   = (const float*)d_in[4];
  const float* bq   = (const float*)d_in[5];
  const float* Wk   = (const float*)d_in[6];
  const float* bk   = (const float*)d_in[7];
  const float* Wv   = (const float*)d_in[8];
  const float* bv   = (const float*)d_in[9];

  float* out  = (float*)d_out;                       // [B,NQ,DM]
  float* attn = out  + (size_t)BB*NQ*DM;             // [B,NQ,NK]
  float* va   = attn + (size_t)BB*NQ*NK;             // [B,NK,DM]
  float* kld  = va   + (size_t)BB*NK*DM;             // [1]

  float* qws  = (float*)d_ws;                        // 4 MB
  float* kws  = qws  + (size_t)BB*NQ*DM;             // 4 MB
  float* kTws = kws  + (size_t)BB*NK*DM;             // 4 MB
  float* klws = kTws + (size_t)BB*DM*NK;             // 8 KB

  dim3 gA((BB*NQ)/4, 3);
  hipLaunchKernelGGL(mlp3_kernel, gA, dim3(256), 0, stream,
                     y, x, Wq, bq, Wk, bk, Wv, bv, qws, kws, va);
  hipLaunchKernelGGL(ktrans_kernel, dim3(NK/64, BB), dim3(256), 0, stream, kws, kTws);
  hipLaunchKernelGGL(bayes_main_kernel, dim3(BB*(NQ/QT)), dim3(256), 0, stream,
                     qws, kTws, va, mask, eps, out, attn, klws);
  hipLaunchKernelGGL(kld_reduce_kernel, dim3(1), dim3(256), 0, stream, klws, kld);
}